// Round 13
// baseline (942.882 us; speedup 1.0000x reference)
//
#include <hip/hip_runtime.h>

// GRU scan: B=2048, T=2048, D=3, H=32. out[b,t] = h_new[b,t][0].
// Round-15: gate-split, VALU-only recurrence, 2 waves/SIMD.
// Decisive R14 null: at 1 wave/SIMD, wall is invariant to inst count
// (110->62 dot insts, same 700cy) -> bubble-bound. R6 (VALU-only,
// 2 waves/SIMD) saturated at 2.13 cy/inst. Combine both lessons:
//  - 1 seq/wave, grid 2048 -> 2 waves/SIMD (TLP hides bubbles);
//  - lanes = (q=lane&31, g=lane>>5); BOTH halves carry mirrored h[q]
//    (no carry-fix): g0 owns r-row(q), g1 owns z-row(q), full K=32;
//    one shared sigmoid instruction computes r (g0) and z (g1);
//  - n-row: per-half 16-k slice via ZERO-PADDED weights (branchless,
//    no runtime-indexed arrays), combined with 1 permlane32_swap;
//  - gather: 15 DPP own row + permlane16_swap + 15 DPP other row,
//    written directly into f32x2 halves; dots = 32 pk_fma, 4 chains;
//  - x: R10 one-step-ahead LDS prefetch (only DS ops in the loop);
//  - probes (dir/p16/p32) ballot-verified; fallback = R9 gru_simple.

#define GRU_B 2048
#define GRU_T 2048
#define GRU_D 3
#define GRU_H 32
#define CHUNK 32

typedef unsigned int uint2v __attribute__((ext_vector_type(2)));
typedef float f32x2 __attribute__((ext_vector_type(2)));

__device__ __forceinline__ float fast_sigmoid(float x) {
    float e = __expf(-x);                    // v_mul(log2e)+v_exp
    return __builtin_amdgcn_rcpf(1.0f + e);  // e=inf -> 0 (correct limit)
}
__device__ __forceinline__ float fast_tanh(float x) {
    float e = __expf(2.0f * x);              // overflow -> inf -> tanh=1
    return 1.0f - 2.0f * __builtin_amdgcn_rcpf(e + 1.0f);
}
__device__ __forceinline__ float bperm(float v, int baddr) {
    return __int_as_float(__builtin_amdgcn_ds_bpermute(baddr, __float_as_int(v)));
}

// DPP row_ror:N = 0x120+N; all rows/banks, no bound ctrl.
#define DPPF(v, CTRL) __int_as_float(__builtin_amdgcn_update_dpp( \
    0, __float_as_int(v), (CTRL), 0xF, 0xF, false))

template<bool SEL>
__device__ __forceinline__ float swap32(float v) {
    uint2v r = __builtin_amdgcn_permlane32_swap(
        __float_as_uint(v), __float_as_uint(v), false, false);
    return __uint_as_float(SEL ? r.x : r.y);
}

#if __has_builtin(__builtin_amdgcn_permlane16_swap)
#define HAVE_P16 1
#else
#define HAVE_P16 0
#endif

// ---------------- fast path: gate-split, mirrored register h ----------------
template<bool SEL32, bool USE16>
__device__ void gru_fast(
    const float* __restrict__ xp, float* __restrict__ ob,
    const float* __restrict__ w_ih, const float* __restrict__ w_hh,
    const float* __restrict__ bias, const float* __restrict__ bias_n,
    float* __restrict__ x_lds, int lane, int dir, bool sel16, int a16)
{
    const int q     = lane & 31;   // owned unit (mirrored across halves)
    const int g     = lane >> 5;   // 0: r-gate owner, 1: z-gate owner
    const int qr    = q & 15;      // position within 16-row
    const int rbase = q & 16;      // own row's k-base

    // slot s (0..31): value h[k(s)] available after gather.
    //   s<16 : own-row rotation s      -> k = rbase | ((qr+dir*s)&15)
    //   s>=16: swapped-row rotation s-16 -> k = (rbase^16) | ((qr+dir*s)&15)
    const int rowG = 32 * g + q;       // my sigmoid gate row (r / z)
    const int rowN = 2 * GRU_H + q;    // n gate row
    f32x2 wg[16], wn[16];
#pragma unroll
    for (int i2 = 0; i2 < 16; ++i2) {
        const int s0 = 2 * i2, s1 = 2 * i2 + 1;
        const int b0 = (s0 < 16) ? rbase : (rbase ^ 16);
        const int b1 = (s1 < 16) ? rbase : (rbase ^ 16);
        const int k0 = b0 | ((qr + dir * (s0 & 15) + 32) & 15);
        const int k1 = b1 | ((qr + dir * (s1 & 15) + 32) & 15);
        wg[i2] = f32x2{w_hh[(size_t)rowG * GRU_H + k0],
                       w_hh[(size_t)rowG * GRU_H + k1]};
        // n-row slice: this half covers k in [16g, 16g+16); zero-pad rest.
        const float n0 = ((k0 >> 4) == g) ? w_hh[(size_t)rowN * GRU_H + k0] : 0.0f;
        const float n1 = ((k1 >> 4) == g) ? w_hh[(size_t)rowN * GRU_H + k1] : 0.0f;
        wn[i2] = f32x2{n0, n1};
    }
    float wiM[GRU_D], wiN[GRU_D];
#pragma unroll
    for (int d = 0; d < GRU_D; ++d) {
        wiM[d] = w_ih[(size_t)rowG * GRU_D + d];
        wiN[d] = w_ih[(size_t)rowN * GRU_D + d];
    }
    const float bM = bias[rowG];
    const float bN = bias[rowN] + bias_n[q];

    float h = 0.0f;  // mirrored trajectory: valid in BOTH halves
    // chunk-0 global prefetch (96 floats: 64 + 32 lanes)
    float xr0 = xp[lane];
    float xr1 = (lane < 32) ? xp[64 + lane] : 0.0f;

    for (int c = 0; c < GRU_T / CHUNK; ++c) {
        x_lds[lane] = xr0;
        if (lane < 32) x_lds[64 + lane] = xr1;
        if (c + 1 < GRU_T / CHUNK) {
            const size_t nb = (size_t)(c + 1) * (CHUNK * GRU_D);
            xr0 = xp[nb + lane];
            xr1 = (lane < 32) ? xp[nb + 64 + lane] : 0.0f;
        }
        // step-0 x (ordered behind staging in the same-wave DS queue)
        float x0c = x_lds[0], x1c = x_lds[1], x2c = x_lds[2];
        float outreg = 0.0f;

#pragma unroll 8
        for (int s = 0; s < CHUNK; ++s) {
            // projections consume x prefetched one step ago (no stall)
            const float aM = fmaf(wiM[2], x2c, fmaf(wiM[1], x1c, fmaf(wiM[0], x0c, bM)));
            const float aN = fmaf(wiN[2], x2c, fmaf(wiN[1], x1c, fmaf(wiN[0], x0c, bN)));

            // issue next step's x reads (consumed next iteration)
            float x0n = x0c, x1n = x1c, x2n = x2c;
            if (s + 1 < CHUNK) {
                x0n = x_lds[3 * (s + 1) + 0];
                x1n = x_lds[3 * (s + 1) + 1];
                x2n = x_lds[3 * (s + 1) + 2];
            }

            // other-row source: lane^16 partner's h (same half)
            float hs;
            if constexpr (USE16) {
#if HAVE_P16
                uint2v f = __builtin_amdgcn_permlane16_swap(
                    __float_as_uint(h), __float_as_uint(h), false, false);
                hs = __uint_as_float(sel16 ? f.x : f.y);
#else
                hs = bperm(h, a16);
#endif
            } else {
                hs = bperm(h, a16);
            }

            // gather: rotations written straight into f32x2 halves
            f32x2 hh[16];
            hh[0].x  = h;                hh[0].y  = DPPF(h, 0x121);
            hh[1].x  = DPPF(h, 0x122);   hh[1].y  = DPPF(h, 0x123);
            hh[2].x  = DPPF(h, 0x124);   hh[2].y  = DPPF(h, 0x125);
            hh[3].x  = DPPF(h, 0x126);   hh[3].y  = DPPF(h, 0x127);
            hh[4].x  = DPPF(h, 0x128);   hh[4].y  = DPPF(h, 0x129);
            hh[5].x  = DPPF(h, 0x12A);   hh[5].y  = DPPF(h, 0x12B);
            hh[6].x  = DPPF(h, 0x12C);   hh[6].y  = DPPF(h, 0x12D);
            hh[7].x  = DPPF(h, 0x12E);   hh[7].y  = DPPF(h, 0x12F);
            hh[8].x  = hs;               hh[8].y  = DPPF(hs, 0x121);
            hh[9].x  = DPPF(hs, 0x122);  hh[9].y  = DPPF(hs, 0x123);
            hh[10].x = DPPF(hs, 0x124);  hh[10].y = DPPF(hs, 0x125);
            hh[11].x = DPPF(hs, 0x126);  hh[11].y = DPPF(hs, 0x127);
            hh[12].x = DPPF(hs, 0x128);  hh[12].y = DPPF(hs, 0x129);
            hh[13].x = DPPF(hs, 0x12A);  hh[13].y = DPPF(hs, 0x12B);
            hh[14].x = DPPF(hs, 0x12C);  hh[14].y = DPPF(hs, 0x12D);
            hh[15].x = DPPF(hs, 0x12E);  hh[15].y = DPPF(hs, 0x12F);

            // 32 pk_fma (64 MACs/lane), 4 independent chains
            f32x2 ag0 = f32x2{aM, 0.0f}, ag1 = f32x2{0.0f, 0.0f};
            f32x2 an0 = f32x2{0.0f, 0.0f}, an1 = f32x2{0.0f, 0.0f};
#pragma unroll
            for (int i2 = 0; i2 < 8; ++i2) {
                ag0 = __builtin_elementwise_fma(wg[i2],     hh[i2],     ag0);
                ag1 = __builtin_elementwise_fma(wg[i2 + 8], hh[i2 + 8], ag1);
                an0 = __builtin_elementwise_fma(wn[i2],     hh[i2],     an0);
                an1 = __builtin_elementwise_fma(wn[i2 + 8], hh[i2 + 8], an1);
            }
            const f32x2 agv = ag0 + ag1;        // pk_add
            const f32x2 anv = an0 + an1;
            const float sG = agv.x + agv.y;     // full gate sum (r / z)
            const float Np = anv.x + anv.y;     // my n K-half
            const float gN = Np + swap32<SEL32>(Np);  // full n hh-dot

            const float sg    = fast_sigmoid(sG);     // g0: r, g1: z
            const float other = swap32<SEL32>(sg);    // g0: z, g1: r
            const float rr = g ? other : sg;
            const float zz = g ? sg : other;
            const float n  = fast_tanh(fmaf(rr, gN, aN));
            const float hnew = fmaf(zz, h - n, n);    // (1-z)*n + z*h

            // capture out[t] = h_new[t][0]: lane 0 holds unit 0
            const float h0 = __uint_as_float(
                (unsigned)__builtin_amdgcn_readfirstlane(__float_as_int(hnew)));
            if (lane == s) outreg = h0;

            h = hnew;   // both halves keep valid mirrored trajectory
            x0c = x0n; x1c = x1n; x2c = x2n;
        }
        if (lane < CHUNK) ob[c * CHUNK + lane] = outreg;  // 128B coalesced
    }
}

// ------------- fallback (probe failure only): lanes 0-31, LDS h -------------
__device__ void gru_simple(
    const float* __restrict__ xp, float* __restrict__ ob,
    const float* __restrict__ w_ih, const float* __restrict__ w_hh,
    const float* __restrict__ bias, const float* __restrict__ bias_n,
    float* __restrict__ x_lds, float* __restrict__ h2, int lane)
{
    const int p = lane & 31;
    float wr[32], wz[32], wn[32];
#pragma unroll
    for (int k = 0; k < 32; ++k) {
        wr[k] = w_hh[(size_t)p * GRU_H + k];
        wz[k] = w_hh[(size_t)(GRU_H + p) * GRU_H + k];
        wn[k] = w_hh[(size_t)(2 * GRU_H + p) * GRU_H + k];
    }
    float wir[GRU_D], wiz[GRU_D], win[GRU_D];
#pragma unroll
    for (int d = 0; d < GRU_D; ++d) {
        wir[d] = w_ih[(size_t)p * GRU_D + d];
        wiz[d] = w_ih[(size_t)(GRU_H + p) * GRU_D + d];
        win[d] = w_ih[(size_t)(2 * GRU_H + p) * GRU_D + d];
    }
    const float bR = bias[p];
    const float bZ = bias[GRU_H + p];
    const float bN = bias[2 * GRU_H + p] + bias_n[p];

    float h = 0.0f;
    if (lane < 32) h2[lane] = 0.0f;
    __builtin_amdgcn_s_waitcnt(0xC07F);

    float xr0 = xp[lane];
    float xr1 = (lane < 32) ? xp[64 + lane] : 0.0f;

    for (int c = 0; c < GRU_T / CHUNK; ++c) {
        x_lds[lane] = xr0;
        if (lane < 32) x_lds[64 + lane] = xr1;
        if (c + 1 < GRU_T / CHUNK) {
            const size_t nb = (size_t)(c + 1) * (CHUNK * GRU_D);
            xr0 = xp[nb + lane];
            xr1 = (lane < 32) ? xp[nb + 64 + lane] : 0.0f;
        }
        float outreg = 0.0f;
#pragma unroll 4
        for (int s = 0; s < CHUNK; ++s) {
            const float x0 = x_lds[3 * s + 0];
            const float x1 = x_lds[3 * s + 1];
            const float x2 = x_lds[3 * s + 2];
            float4 hk[8];
            const float4* hv = (const float4*)h2;
#pragma unroll
            for (int qq = 0; qq < 8; ++qq) hk[qq] = hv[qq];

            const float aR = fmaf(wir[2], x2, fmaf(wir[1], x1, fmaf(wir[0], x0, bR)));
            const float aZ = fmaf(wiz[2], x2, fmaf(wiz[1], x1, fmaf(wiz[0], x0, bZ)));
            const float aN = fmaf(win[2], x2, fmaf(win[1], x1, fmaf(win[0], x0, bN)));

            float r0 = aR, z0 = aZ, n0 = 0.f;
#pragma unroll
            for (int qq = 0; qq < 8; ++qq) {
                const float4 v = hk[qq];
                r0 = fmaf(wr[4*qq+0], v.x, r0); r0 = fmaf(wr[4*qq+1], v.y, r0);
                r0 = fmaf(wr[4*qq+2], v.z, r0); r0 = fmaf(wr[4*qq+3], v.w, r0);
                z0 = fmaf(wz[4*qq+0], v.x, z0); z0 = fmaf(wz[4*qq+1], v.y, z0);
                z0 = fmaf(wz[4*qq+2], v.z, z0); z0 = fmaf(wz[4*qq+3], v.w, z0);
                n0 = fmaf(wn[4*qq+0], v.x, n0); n0 = fmaf(wn[4*qq+1], v.y, n0);
                n0 = fmaf(wn[4*qq+2], v.z, n0); n0 = fmaf(wn[4*qq+3], v.w, n0);
            }
            const float rg = fast_sigmoid(r0);
            const float zg = fast_sigmoid(z0);
            const float ng = fast_tanh(fmaf(rg, n0, aN));
            const float hnew = fmaf(zg, h - ng, ng);
            const float h0 = __uint_as_float(
                (unsigned)__builtin_amdgcn_readfirstlane(__float_as_int(hnew)));
            if (lane == s) outreg = h0;
            h = hnew;
            if (lane < 32) h2[lane] = h;
        }
        if (lane < CHUNK) ob[c * CHUNK + lane] = outreg;
    }
}

__global__ __launch_bounds__(64, 2) void gru_scan_kernel(
    const float* __restrict__ inp, const float* __restrict__ w_ih,
    const float* __restrict__ w_hh, const float* __restrict__ bias,
    const float* __restrict__ bias_n, float* __restrict__ out)
{
    __shared__ __align__(16) float x_lds[CHUNK * GRU_D];  // 96 floats
    __shared__ __align__(16) float h2[GRU_H];             // fallback only

    const int lane = threadIdx.x;  // 0..63
    const size_t seq = blockIdx.x; // 1 seq per wave

    const float* xp = inp + seq * (size_t)(GRU_T * GRU_D);
    float*       ob = out + seq * (size_t)GRU_T;
    const int a16 = (lane ^ 16) << 2;

    // ---- one-time probes (ballot-verified, wave-uniform) ----
    int dir = 0;
    bool ok32 = false, sel32 = false, ok16 = false, sel16 = false;
    {
        const int li = lane & 15;
        const int d1 = __builtin_amdgcn_update_dpp(0, li, 0x121, 0xF, 0xF, false);
        if (__ballot(d1 == ((li + 1) & 15)) == ~0ULL)       dir = 1;
        else if (__ballot(d1 == ((li + 15) & 15)) == ~0ULL) dir = -1;

        const unsigned ul = (unsigned)lane;
        uint2v q = __builtin_amdgcn_permlane32_swap(ul, ul, false, false);
        const unsigned w32 = ul ^ 32u;
        const bool a = __ballot(q.x == w32) == ~0ULL;
        const bool b = __ballot(q.y == w32) == ~0ULL;
        ok32 = a || b; sel32 = a;

#if HAVE_P16
        uint2v q16 = __builtin_amdgcn_permlane16_swap(ul, ul, false, false);
        const unsigned w16 = ul ^ 16u;
        const bool a16ok = __ballot(q16.x == w16) == ~0ULL;
        const bool b16ok = __ballot(q16.y == w16) == ~0ULL;
        ok16 = a16ok || b16ok; sel16 = a16ok;
#endif
    }

    if (dir != 0 && ok32) {
        if (ok16) {
            if (sel32) gru_fast<true,  true >(xp, ob, w_ih, w_hh, bias, bias_n,
                                              x_lds, lane, dir, sel16, a16);
            else       gru_fast<false, true >(xp, ob, w_ih, w_hh, bias, bias_n,
                                              x_lds, lane, dir, sel16, a16);
        } else {
            if (sel32) gru_fast<true,  false>(xp, ob, w_ih, w_hh, bias, bias_n,
                                              x_lds, lane, dir, sel16, a16);
            else       gru_fast<false, false>(xp, ob, w_ih, w_hh, bias, bias_n,
                                              x_lds, lane, dir, sel16, a16);
        }
    } else {
        gru_simple(xp, ob, w_ih, w_hh, bias, bias_n, x_lds, h2, lane);
    }
}

extern "C" void kernel_launch(void* const* d_in, const int* in_sizes, int n_in,
                              void* d_out, int out_size, void* d_ws, size_t ws_size,
                              hipStream_t stream) {
    const float* inp    = (const float*)d_in[0];
    const float* w_ih   = (const float*)d_in[1];
    const float* w_hh   = (const float*)d_in[2];
    const float* bias   = (const float*)d_in[3];
    const float* bias_n = (const float*)d_in[4];
    float* out = (float*)d_out;

    dim3 grid(GRU_B);
    dim3 block(64);
    gru_scan_kernel<<<grid, block, 0, stream>>>(inp, w_ih, w_hh, bias, bias_n, out);
}